// Round 11
// baseline (1717.025 us; speedup 1.0000x reference)
//
#include <hip/hip_runtime.h>
#include <hip/hip_bf16.h>

#define NB 8
#define LSEQ 2048
#define HH 8
#define DD 32
#define EE 256
#define NE 32

// zinv geometry (round-8 proven)
#define ZQT 64
#define ZNT 512
#define ZKW 256
#define ZNTILE 16

// mean+topk geometry: 64 queries x 256-key chunk per block, 8 waves
#define MQT 64
#define MNT 512
#define MKC 256    // keys per chunk (block)
#define NCHUNK 8   // chunks per row
#define SMS2 258   // smean row stride (words); 258%32==2 -> 2-way banks (free)

typedef __attribute__((ext_vector_type(8))) short short8;
typedef __attribute__((ext_vector_type(4))) float f32x4;

// ---------------------------------------------------------------------------
// K1: per-head projection -> 3-way bf16 split (hi/mid/lo ~ 24 mantissa bits).
// Q pass folds softmax temperature AND 1/ln2: scale = 1/(16*ln2) -> exp2.
// ---------------------------------------------------------------------------
__global__ __launch_bounds__(256) void proj_kernel(const float* __restrict__ x,
                                                   const float* __restrict__ W,
                                                   float scale,
                                                   __hip_bfloat16* __restrict__ o1,
                                                   __hip_bfloat16* __restrict__ o2,
                                                   __hip_bfloat16* __restrict__ o3) {
  const int b = blockIdx.x;  // n*L + l
  __shared__ float xs[EE];
  __shared__ float Ws[DD][DD + 1];
  const int t = threadIdx.x;
  xs[t] = x[(size_t)b * EE + t];
  for (int i = t; i < DD * DD; i += 256) Ws[i / DD][i % DD] = W[i];
  __syncthreads();
  const int h = t / DD, e = t % DD;
  float acc = 0.f;
#pragma unroll
  for (int d = 0; d < DD; ++d) acc = fmaf(xs[h * DD + d], Ws[e][d], acc);
  acc *= scale;
  const int n = b / LSEQ, l = b % LSEQ;
  const size_t oi = (((size_t)n * HH + h) * LSEQ + l) * DD + e;
  __hip_bfloat16 p1 = __float2bfloat16(acc);
  float r1 = acc - __bfloat162float(p1);
  __hip_bfloat16 p2 = __float2bfloat16(r1);
  float r2 = r1 - __bfloat162float(p2);
  __hip_bfloat16 p3 = __float2bfloat16(r2);
  o1[oi] = p1;
  o2[oi] = p2;
  o3[oi] = p3;
}

// ---------------------------------------------------------------------------
// K2: Z -> inv = rcp(Z) (round-8 proven, unchanged).
// inv is a per-(h,row) uniform scale: order-safe in any summation order.
// ---------------------------------------------------------------------------
__global__ __launch_bounds__(ZNT) void zinv_kernel(
    const __hip_bfloat16* __restrict__ q1, const __hip_bfloat16* __restrict__ q2,
    const __hip_bfloat16* __restrict__ q3, const __hip_bfloat16* __restrict__ k1,
    const __hip_bfloat16* __restrict__ k2, const __hip_bfloat16* __restrict__ k3,
    float* __restrict__ invp) {
  __shared__ float zlds[HH][ZQT];

  const int t = threadIdx.x;
  const int w = t >> 6, l = t & 63;
  const int g = l >> 4, c = l & 15;
  const int n = blockIdx.x & 7;
  const int q0 = (blockIdx.x >> 3) * ZQT;

  ((float*)zlds)[t] = 0.f;
  __syncthreads();

  for (int h = 0; h < HH; ++h) {
    const size_t hb = ((size_t)n * HH + h) * LSEQ;
    short8 aH[4], aM[4], aL[4];
#pragma unroll
    for (int qs = 0; qs < 4; ++qs) {
      const size_t qoff = (hb + q0 + qs * 16 + c) * DD + (size_t)g * 8;
      aH[qs] = *(const short8*)(q1 + qoff);
      aM[qs] = *(const short8*)(q2 + qoff);
      aL[qs] = *(const short8*)(q3 + qoff);
    }
    float Zl[4][4];
#pragma unroll
    for (int qs = 0; qs < 4; ++qs)
#pragma unroll
      for (int r = 0; r < 4; ++r) Zl[qs][r] = 0.f;

    for (int t2 = 0; t2 < ZNTILE; ++t2) {
      const size_t koff = (hb + (size_t)w * ZKW + t2 * 16 + c) * DD + (size_t)g * 8;
      const short8 bH = *(const short8*)(k1 + koff);
      const short8 bM = *(const short8*)(k2 + koff);
      const short8 bL = *(const short8*)(k3 + koff);
#pragma unroll
      for (int qs = 0; qs < 4; ++qs) {
        f32x4 a = {0.f, 0.f, 0.f, 0.f};
        a = __builtin_amdgcn_mfma_f32_16x16x32_bf16(aH[qs], bH, a, 0, 0, 0);
        a = __builtin_amdgcn_mfma_f32_16x16x32_bf16(aH[qs], bM, a, 0, 0, 0);
        a = __builtin_amdgcn_mfma_f32_16x16x32_bf16(aM[qs], bH, a, 0, 0, 0);
        a = __builtin_amdgcn_mfma_f32_16x16x32_bf16(aH[qs], bL, a, 0, 0, 0);
        a = __builtin_amdgcn_mfma_f32_16x16x32_bf16(aL[qs], bH, a, 0, 0, 0);
        a = __builtin_amdgcn_mfma_f32_16x16x32_bf16(aM[qs], bM, a, 0, 0, 0);
#pragma unroll
        for (int r = 0; r < 4; ++r) Zl[qs][r] += exp2f(a[r]);
      }
    }
#pragma unroll
    for (int msk = 1; msk <= 8; msk <<= 1)
#pragma unroll
      for (int qs = 0; qs < 4; ++qs)
#pragma unroll
        for (int r = 0; r < 4; ++r) Zl[qs][r] += __shfl_xor(Zl[qs][r], msk);
    if (c == 0) {
#pragma unroll
      for (int qs = 0; qs < 4; ++qs)
#pragma unroll
        for (int r = 0; r < 4; ++r) atomicAdd(&zlds[h][qs * 16 + g * 4 + r], Zl[qs][r]);
    }
  }
  __syncthreads();
  const int h2 = t >> 6, qi = t & 63;
  invp[((size_t)n * HH + h2) * LSEQ + q0 + qi] = __builtin_amdgcn_rcpf(zlds[h2][qi]);
}

// ---------------------------------------------------------------------------
// K3: 64-query x 256-key chunk mean (REGISTER accumulator) + chunk top-32.
// zinv's amortization applied to the mean pass: each K fragment is reused by
// 4 query-subtiles -> K traffic 0.8 GB total (was 3.2 GB), the 8 TB/s L2
// bound's lever. Head loop: Q frags (48 regs) reload per head; macc[2][4][4]
// (32 regs) persists across heads; NO LDS in the loop. After heads: one store
// to smean (66 KB -> 2 blocks/CU), then proven per-chunk top-32 -> candidates.
// C fragment mapping (verified rounds 2-10): row(query)=g*4+r, col(key)=c.
// ---------------------------------------------------------------------------
__global__ __launch_bounds__(MNT) void mean_topk_kernel(
    const __hip_bfloat16* __restrict__ q1, const __hip_bfloat16* __restrict__ q2,
    const __hip_bfloat16* __restrict__ q3, const __hip_bfloat16* __restrict__ k1,
    const __hip_bfloat16* __restrict__ k2, const __hip_bfloat16* __restrict__ k3,
    const float* __restrict__ invp, float* __restrict__ candV,
    unsigned short* __restrict__ candI) {
  __shared__ float smean[MQT * SMS2];  // 66 KB (no init needed: fully overwritten)
  __shared__ float ilds[HH][MQT];      // 2 KB

  const int t = threadIdx.x;
  const int w = t >> 6, l = t & 63;
  const int g = l >> 4, c = l & 15;
  const int n = blockIdx.x & 7;       // 2048 blocks, %8==0: bijective XCD map
  const int rest = blockIdx.x >> 3;   // 0..255
  const int qt = rest & 31;           // 0..31
  const int kq = rest >> 5;           // 0..7
  const int q0 = qt * MQT;
  const int k0 = kq * MKC;

  {  // preload inv: 512 threads == HH*MQT elements
    const int h = t >> 6, qi = t & 63;
    ilds[h][qi] = invp[((size_t)n * HH + h) * LSEQ + q0 + qi];
  }
  __syncthreads();

  float macc[2][4][4];  // [t2][qs][r] mean accumulator (static indexing only)
#pragma unroll
  for (int t2 = 0; t2 < 2; ++t2)
#pragma unroll
    for (int qs = 0; qs < 4; ++qs)
#pragma unroll
      for (int r = 0; r < 4; ++r) macc[t2][qs][r] = 0.f;

  for (int h = 0; h < HH; ++h) {
    const size_t hb = ((size_t)n * HH + h) * LSEQ;
    short8 aH[4], aM[4], aL[4];
#pragma unroll
    for (int qs = 0; qs < 4; ++qs) {
      const size_t qoff = (hb + q0 + qs * 16 + c) * DD + (size_t)g * 8;
      aH[qs] = *(const short8*)(q1 + qoff);
      aM[qs] = *(const short8*)(q2 + qoff);
      aL[qs] = *(const short8*)(q3 + qoff);
    }
#pragma unroll
    for (int t2 = 0; t2 < 2; ++t2) {
      // wave w owns keys [k0 + w*32, k0 + (w+1)*32)
      const size_t koff = (hb + k0 + (size_t)w * 32 + t2 * 16 + c) * DD + (size_t)g * 8;
      const short8 bH = *(const short8*)(k1 + koff);
      const short8 bM = *(const short8*)(k2 + koff);
      const short8 bL = *(const short8*)(k3 + koff);
#pragma unroll
      for (int qs = 0; qs < 4; ++qs) {
        f32x4 a = {0.f, 0.f, 0.f, 0.f};
        a = __builtin_amdgcn_mfma_f32_16x16x32_bf16(aH[qs], bH, a, 0, 0, 0);
        a = __builtin_amdgcn_mfma_f32_16x16x32_bf16(aH[qs], bM, a, 0, 0, 0);
        a = __builtin_amdgcn_mfma_f32_16x16x32_bf16(aM[qs], bH, a, 0, 0, 0);
        a = __builtin_amdgcn_mfma_f32_16x16x32_bf16(aH[qs], bL, a, 0, 0, 0);
        a = __builtin_amdgcn_mfma_f32_16x16x32_bf16(aL[qs], bH, a, 0, 0, 0);
        a = __builtin_amdgcn_mfma_f32_16x16x32_bf16(aM[qs], bM, a, 0, 0, 0);
        const f32x4 iv = *(const f32x4*)&ilds[h][qs * 16 + g * 4];  // broadcast
#pragma unroll
        for (int r = 0; r < 4; ++r)
          macc[t2][qs][r] = fmaf(exp2f(a[r]), iv[r], macc[t2][qs][r]);
      }
    }
  }

  // --- one store of the chunk-mean to LDS (2-way banks: free) ---
#pragma unroll
  for (int t2 = 0; t2 < 2; ++t2)
#pragma unroll
    for (int qs = 0; qs < 4; ++qs)
#pragma unroll
      for (int r = 0; r < 4; ++r)
        smean[(qs * 16 + g * 4 + r) * SMS2 + w * 32 + t2 * 16 + c] = macc[t2][qs][r];
  __syncthreads();

  // --- per-chunk top-32: wave w owns rows w*8..w*8+7; local k = j*64 + l ---
#pragma unroll 1
  for (int rr = 0; rr < 8; ++rr) {
    const int row = w * 8 + rr;
    float* rowp = &smean[row * SMS2];
    float vals[4];
    float v1 = -1e30f, v2 = -1e30f;
    int i1 = 1 << 30, i2 = 1 << 30;
#pragma unroll
    for (int j = 0; j < 4; ++j) {
      float v = rowp[j * 64 + l];
      vals[j] = v;
      const int k = j * 64 + l;
      if (v > v1) { v2 = v1; i2 = i1; v1 = v; i1 = k; }
      else if (v > v2) { v2 = v; i2 = k; }
    }
    unsigned rem = 0u;
    int selk = 0;
    float selv = 0.f;
#pragma unroll 1
    for (int it = 0; it < NE; ++it) {
      float bv = v1;
      int bk = i1;
#pragma unroll
      for (int off = 32; off >= 1; off >>= 1) {
        float ov = __shfl_xor(bv, off);
        int ok = __shfl_xor(bk, off);
        if (ov > bv || (ov == bv && ok < bk)) { bv = ov; bk = ok; }
      }
      if (l == it) { selk = bk; selv = bv; }
      if (i1 == bk) {  // this lane supplied the winner (k%64==l: unique owner)
        rem |= 1u << (bk >> 6);
        if (i2 != (1 << 30)) {  // promote cached second
          v1 = v2; i1 = i2;
          v2 = -1e30f; i2 = 1 << 30;
        } else {  // rare: rebuild top-2 from masked registers
          v1 = -1e30f; i1 = 1 << 30;
          v2 = -1e30f; i2 = 1 << 30;
#pragma unroll
          for (int j = 0; j < 4; ++j) {
            float v = ((rem >> j) & 1u) ? -1e30f : vals[j];
            const int k = j * 64 + l;
            if (v > v1) { v2 = v1; i2 = i1; v1 = v; i1 = k; }
            else if (v > v2) { v2 = v; i2 = k; }
          }
        }
      }
    }
    if (l < NE) {
      const size_t cb = (((size_t)n * LSEQ + q0 + row) * NCHUNK + kq) * NE;
      candV[cb + l] = selv;
      candI[cb + l] = (unsigned short)(k0 + selk);  // global key index (<2048)
    }
  }
}

// ---------------------------------------------------------------------------
// K4: merge 8x32 chunk candidates per row (4 per lane) -> final top-32 ->
// sorted edges. Same (val desc, idx asc) tie semantics; key indices unique.
// ---------------------------------------------------------------------------
__global__ __launch_bounds__(512) void merge_kernel(const float* __restrict__ candV,
                                                    const unsigned short* __restrict__ candI,
                                                    int* __restrict__ out) {
  const int t = threadIdx.x;
  const int w = t >> 6, l = t & 63;
  const size_t rowg = (size_t)blockIdx.x * 8 + w;  // n*2048 + q
  const int n = (int)(rowg >> 11), q = (int)(rowg & 2047);
  const size_t base = rowg * (NCHUNK * NE);  // 256 candidates

  float v[4];
  int idx[4];
#pragma unroll
  for (int j = 0; j < 4; ++j) {
    v[j] = candV[base + j * 64 + l];
    idx[j] = (int)candI[base + j * 64 + l];
  }

  int selk = 0;
#pragma unroll 1
  for (int it = 0; it < NE; ++it) {
    float bv = v[0];
    int bi = idx[0];
#pragma unroll
    for (int j = 1; j < 4; ++j)
      if (v[j] > bv || (v[j] == bv && idx[j] < bi)) { bv = v[j]; bi = idx[j]; }
#pragma unroll
    for (int off = 32; off >= 1; off >>= 1) {
      float ov = __shfl_xor(bv, off);
      int oi = __shfl_xor(bi, off);
      if (ov > bv || (ov == bv && oi < bi)) { bv = ov; bi = oi; }
    }
    if (l == it) selk = bi;
#pragma unroll
    for (int j = 0; j < 4; ++j)
      if (idx[j] == bi) v[j] = -1e30f;  // remove winner (unique key idx per row)
  }

  int rank = 0;
#pragma unroll
  for (int j = 0; j < NE; ++j) {
    int o = __shfl(selk, j);
    rank += (o < selk) ? 1 : 0;
  }
  if (l < NE) {
    int* o0 = out + (size_t)n * 2 * LSEQ * NE + (size_t)q * NE;
    int* o1p = o0 + (size_t)LSEQ * NE;
    o0[l] = q;
    o1p[rank] = selk;
  }
}

// ---------------------------------------------------------------------------
extern "C" void kernel_launch(void* const* d_in, const int* in_sizes, int n_in,
                              void* d_out, int out_size, void* d_ws, size_t ws_size,
                              hipStream_t stream) {
  const float* keys = (const float*)d_in[0];
  const float* query = (const float*)d_in[1];
  const float* Wk = (const float*)d_in[2];
  const float* Wq = (const float*)d_in[3];
  int* out = (int*)d_out;

  const size_t SPLIT = (size_t)NB * HH * LSEQ * DD;  // 4,194,304 elems
  __hip_bfloat16* qs1 = (__hip_bfloat16*)d_ws;
  __hip_bfloat16* qs2 = qs1 + SPLIT;
  __hip_bfloat16* qs3 = qs2 + SPLIT;
  __hip_bfloat16* ks1 = qs3 + SPLIT;
  __hip_bfloat16* ks2 = ks1 + SPLIT;
  __hip_bfloat16* ks3 = ks2 + SPLIT;
  float* invp = (float*)(ks3 + SPLIT);                         // 512 KB
  float* candV = invp + (size_t)NB * HH * LSEQ;                // 16.8 MB
  unsigned short* candI =
      (unsigned short*)(candV + (size_t)NB * LSEQ * NCHUNK * NE);  // 8.4 MB

  proj_kernel<<<NB * LSEQ, 256, 0, stream>>>(query, Wq, 0.0625f * 1.44269504088896340736f,
                                             qs1, qs2, qs3);
  proj_kernel<<<NB * LSEQ, 256, 0, stream>>>(keys, Wk, 1.0f, ks1, ks2, ks3);
  zinv_kernel<<<NB * (LSEQ / ZQT), ZNT, 0, stream>>>(qs1, qs2, qs3, ks1, ks2, ks3, invp);
  mean_topk_kernel<<<NB * (LSEQ / MQT) * NCHUNK, MNT, 0, stream>>>(
      qs1, qs2, qs3, ks1, ks2, ks3, invp, candV, candI);
  merge_kernel<<<NB * LSEQ / 8, 512, 0, stream>>>(candV, candI, out);
}

// Round 12
// 732.897 us; speedup vs baseline: 2.3428x; 2.3428x over previous
//
#include <hip/hip_runtime.h>
#include <hip/hip_bf16.h>

#define NB 8
#define LSEQ 2048
#define HH 8
#define DD 32
#define EE 256
#define NE 32

// zinv geometry (round-8 proven)
#define ZQT 64
#define ZNT 512
#define ZKW 256
#define ZNTILE 16

// mean+topk geometry: 32 queries x 512-key quarter per block, 8 waves
#define MQT 32
#define MNT 512
#define MKC 512
#define NQUART 4
#define MKW 64     // keys per wave
#define MNTILE 4   // MKW / 16
#define SMS3 514   // smean row stride (words); 514%32==2 -> 2-way banks (free)

typedef __attribute__((ext_vector_type(8))) short short8;
typedef __attribute__((ext_vector_type(4))) float f32x4;

// ---------------------------------------------------------------------------
// K1: per-head projection -> 3-way bf16 split (hi/mid/lo ~ 24 mantissa bits).
// Q pass folds softmax temperature AND 1/ln2: scale = 1/(16*ln2) -> exp2.
// ---------------------------------------------------------------------------
__global__ __launch_bounds__(256) void proj_kernel(const float* __restrict__ x,
                                                   const float* __restrict__ W,
                                                   float scale,
                                                   __hip_bfloat16* __restrict__ o1,
                                                   __hip_bfloat16* __restrict__ o2,
                                                   __hip_bfloat16* __restrict__ o3) {
  const int b = blockIdx.x;  // n*L + l
  __shared__ float xs[EE];
  __shared__ float Ws[DD][DD + 1];
  const int t = threadIdx.x;
  xs[t] = x[(size_t)b * EE + t];
  for (int i = t; i < DD * DD; i += 256) Ws[i / DD][i % DD] = W[i];
  __syncthreads();
  const int h = t / DD, e = t % DD;
  float acc = 0.f;
#pragma unroll
  for (int d = 0; d < DD; ++d) acc = fmaf(xs[h * DD + d], Ws[e][d], acc);
  acc *= scale;
  const int n = b / LSEQ, l = b % LSEQ;
  const size_t oi = (((size_t)n * HH + h) * LSEQ + l) * DD + e;
  __hip_bfloat16 p1 = __float2bfloat16(acc);
  float r1 = acc - __bfloat162float(p1);
  __hip_bfloat16 p2 = __float2bfloat16(r1);
  float r2 = r1 - __bfloat162float(p2);
  __hip_bfloat16 p3 = __float2bfloat16(r2);
  o1[oi] = p1;
  o2[oi] = p2;
  o3[oi] = p3;
}

// ---------------------------------------------------------------------------
// K2: Z -> inv = rcp(Z) (round-8 proven, unchanged).
// inv is a per-(h,row) uniform scale: order-safe in any summation order.
// ---------------------------------------------------------------------------
__global__ __launch_bounds__(ZNT) void zinv_kernel(
    const __hip_bfloat16* __restrict__ q1, const __hip_bfloat16* __restrict__ q2,
    const __hip_bfloat16* __restrict__ q3, const __hip_bfloat16* __restrict__ k1,
    const __hip_bfloat16* __restrict__ k2, const __hip_bfloat16* __restrict__ k3,
    float* __restrict__ invp) {
  __shared__ float zlds[HH][ZQT];

  const int t = threadIdx.x;
  const int w = t >> 6, l = t & 63;
  const int g = l >> 4, c = l & 15;
  const int n = blockIdx.x & 7;
  const int q0 = (blockIdx.x >> 3) * ZQT;

  ((float*)zlds)[t] = 0.f;
  __syncthreads();

  for (int h = 0; h < HH; ++h) {
    const size_t hb = ((size_t)n * HH + h) * LSEQ;
    short8 aH[4], aM[4], aL[4];
#pragma unroll
    for (int qs = 0; qs < 4; ++qs) {
      const size_t qoff = (hb + q0 + qs * 16 + c) * DD + (size_t)g * 8;
      aH[qs] = *(const short8*)(q1 + qoff);
      aM[qs] = *(const short8*)(q2 + qoff);
      aL[qs] = *(const short8*)(q3 + qoff);
    }
    float Zl[4][4];
#pragma unroll
    for (int qs = 0; qs < 4; ++qs)
#pragma unroll
      for (int r = 0; r < 4; ++r) Zl[qs][r] = 0.f;

    for (int t2 = 0; t2 < ZNTILE; ++t2) {
      const size_t koff = (hb + (size_t)w * ZKW + t2 * 16 + c) * DD + (size_t)g * 8;
      const short8 bH = *(const short8*)(k1 + koff);
      const short8 bM = *(const short8*)(k2 + koff);
      const short8 bL = *(const short8*)(k3 + koff);
#pragma unroll
      for (int qs = 0; qs < 4; ++qs) {
        f32x4 a = {0.f, 0.f, 0.f, 0.f};
        a = __builtin_amdgcn_mfma_f32_16x16x32_bf16(aH[qs], bH, a, 0, 0, 0);
        a = __builtin_amdgcn_mfma_f32_16x16x32_bf16(aH[qs], bM, a, 0, 0, 0);
        a = __builtin_amdgcn_mfma_f32_16x16x32_bf16(aM[qs], bH, a, 0, 0, 0);
        a = __builtin_amdgcn_mfma_f32_16x16x32_bf16(aH[qs], bL, a, 0, 0, 0);
        a = __builtin_amdgcn_mfma_f32_16x16x32_bf16(aL[qs], bH, a, 0, 0, 0);
        a = __builtin_amdgcn_mfma_f32_16x16x32_bf16(aM[qs], bM, a, 0, 0, 0);
#pragma unroll
        for (int r = 0; r < 4; ++r) Zl[qs][r] += exp2f(a[r]);
      }
    }
#pragma unroll
    for (int msk = 1; msk <= 8; msk <<= 1)
#pragma unroll
      for (int qs = 0; qs < 4; ++qs)
#pragma unroll
        for (int r = 0; r < 4; ++r) Zl[qs][r] += __shfl_xor(Zl[qs][r], msk);
    if (c == 0) {
#pragma unroll
      for (int qs = 0; qs < 4; ++qs)
#pragma unroll
        for (int r = 0; r < 4; ++r) atomicAdd(&zlds[h][qs * 16 + g * 4 + r], Zl[qs][r]);
    }
  }
  __syncthreads();
  const int h2 = t >> 6, qi = t & 63;
  invp[((size_t)n * HH + h2) * LSEQ + q0 + qi] = __builtin_amdgcn_rcpf(zlds[h2][qi]);
}

// ---------------------------------------------------------------------------
// K3: 32-query x 512-key quarter: mean in REGISTERS (macc[4][2][4] = 32 VGPR)
// -> one LDS store -> proven per-row top-32 over 512 -> 32 candidates/quarter.
// 512 thr / 8 waves; wave w owns keys [k0+w*64, k0+(w+1)*64); each K fragment
// amortized over 2 q-subtiles. LDS 66 KB -> 2 blocks/CU; live ~90 VGPR (512-thr
// allocator is fit-to-live per R9, no 64-bin trap). K traffic 1.6 GB (was 3.2).
// C fragment mapping (verified rounds 2-11): row(query)=g*4+r, col(key)=c.
// ---------------------------------------------------------------------------
__global__ __launch_bounds__(MNT) void mean_topk_kernel(
    const __hip_bfloat16* __restrict__ q1, const __hip_bfloat16* __restrict__ q2,
    const __hip_bfloat16* __restrict__ q3, const __hip_bfloat16* __restrict__ k1,
    const __hip_bfloat16* __restrict__ k2, const __hip_bfloat16* __restrict__ k3,
    const float* __restrict__ invp, float* __restrict__ candV,
    unsigned short* __restrict__ candI) {
  __shared__ float smean[MQT * SMS3];  // 65.8 KB (fully overwritten; no init)
  __shared__ float ilds[HH][MQT];      // 1 KB

  const int t = threadIdx.x;
  const int w = t >> 6, l = t & 63;
  const int g = l >> 4, c = l & 15;
  const int n = blockIdx.x & 7;       // 2048 blocks, %8==0: bijective XCD map
  const int rest = blockIdx.x >> 3;   // 0..255
  const int qt = rest & 63;           // 0..63
  const int kq = rest >> 6;           // 0..3
  const int q0 = qt * MQT;
  const int k0 = kq * MKC;

  if (t < HH * MQT) {  // 256 entries
    const int h = t >> 5, qi = t & 31;
    ilds[h][qi] = invp[((size_t)n * HH + h) * LSEQ + q0 + qi];
  }
  __syncthreads();

  float macc[MNTILE][2][4];  // [t2][qs][r], static indexing only
#pragma unroll
  for (int t2 = 0; t2 < MNTILE; ++t2)
#pragma unroll
    for (int qs = 0; qs < 2; ++qs)
#pragma unroll
      for (int r = 0; r < 4; ++r) macc[t2][qs][r] = 0.f;

  for (int h = 0; h < HH; ++h) {
    const size_t hb = ((size_t)n * HH + h) * LSEQ;
    short8 aH[2], aM[2], aL[2];
    f32x4 iv[2];
#pragma unroll
    for (int qs = 0; qs < 2; ++qs) {
      const size_t qoff = (hb + q0 + qs * 16 + c) * DD + (size_t)g * 8;
      aH[qs] = *(const short8*)(q1 + qoff);
      aM[qs] = *(const short8*)(q2 + qoff);
      aL[qs] = *(const short8*)(q3 + qoff);
      iv[qs] = *(const f32x4*)&ilds[h][qs * 16 + g * 4];
    }
#pragma unroll
    for (int t2 = 0; t2 < MNTILE; ++t2) {
      const size_t koff = (hb + k0 + (size_t)w * MKW + t2 * 16 + c) * DD + (size_t)g * 8;
      const short8 bH = *(const short8*)(k1 + koff);
      const short8 bM = *(const short8*)(k2 + koff);
      const short8 bL = *(const short8*)(k3 + koff);
#pragma unroll
      for (int qs = 0; qs < 2; ++qs) {
        f32x4 a = {0.f, 0.f, 0.f, 0.f};
        a = __builtin_amdgcn_mfma_f32_16x16x32_bf16(aH[qs], bH, a, 0, 0, 0);
        a = __builtin_amdgcn_mfma_f32_16x16x32_bf16(aH[qs], bM, a, 0, 0, 0);
        a = __builtin_amdgcn_mfma_f32_16x16x32_bf16(aM[qs], bH, a, 0, 0, 0);
        a = __builtin_amdgcn_mfma_f32_16x16x32_bf16(aH[qs], bL, a, 0, 0, 0);
        a = __builtin_amdgcn_mfma_f32_16x16x32_bf16(aL[qs], bH, a, 0, 0, 0);
        a = __builtin_amdgcn_mfma_f32_16x16x32_bf16(aM[qs], bM, a, 0, 0, 0);
#pragma unroll
        for (int r = 0; r < 4; ++r)
          macc[t2][qs][r] = fmaf(exp2f(a[r]), iv[qs][r], macc[t2][qs][r]);
      }
    }
  }

  // --- one store of the quarter-mean to LDS (2-way banks: free) ---
#pragma unroll
  for (int t2 = 0; t2 < MNTILE; ++t2)
#pragma unroll
    for (int qs = 0; qs < 2; ++qs)
#pragma unroll
      for (int r = 0; r < 4; ++r)
        smean[(qs * 16 + g * 4 + r) * SMS3 + w * MKW + t2 * 16 + c] = macc[t2][qs][r];
  __syncthreads();

  // --- per-row top-32 over the 512 slice (proven code, vals[8]); wave w: rows w*4.. ---
#pragma unroll 1
  for (int rr = 0; rr < 4; ++rr) {
    const int row = w * 4 + rr;
    float* rowp = &smean[row * SMS3];
    float vals[8];
    float v1 = -1e30f, v2 = -1e30f;
    int i1 = 1 << 30, i2 = 1 << 30;
#pragma unroll
    for (int j = 0; j < 8; ++j) {
      float v = rowp[j * 64 + l];
      vals[j] = v;
      const int k = j * 64 + l;
      if (v > v1) { v2 = v1; i2 = i1; v1 = v; i1 = k; }
      else if (v > v2) { v2 = v; i2 = k; }
    }
    unsigned rem = 0u;
    int selk = 0;
    float selv = 0.f;
#pragma unroll 1
    for (int it = 0; it < NE; ++it) {
      float bv = v1;
      int bk = i1;
#pragma unroll
      for (int off = 32; off >= 1; off >>= 1) {
        float ov = __shfl_xor(bv, off);
        int ok = __shfl_xor(bk, off);
        if (ov > bv || (ov == bv && ok < bk)) { bv = ov; bk = ok; }
      }
      if (l == it) { selk = bk; selv = bv; }
      if (i1 == bk) {  // this lane supplied the winner (k%64==l: unique owner)
        rem |= 1u << (bk >> 6);
        if (i2 != (1 << 30)) {  // promote cached second
          v1 = v2; i1 = i2;
          v2 = -1e30f; i2 = 1 << 30;
        } else {  // rare: rebuild top-2 from masked registers
          v1 = -1e30f; i1 = 1 << 30;
          v2 = -1e30f; i2 = 1 << 30;
#pragma unroll
          for (int j = 0; j < 8; ++j) {
            float v = ((rem >> j) & 1u) ? -1e30f : vals[j];
            const int k = j * 64 + l;
            if (v > v1) { v2 = v1; i2 = i1; v1 = v; i1 = k; }
            else if (v > v2) { v2 = v; i2 = k; }
          }
        }
      }
    }
    if (l < NE) {
      const size_t cb = (((size_t)n * LSEQ + q0 + row) * NQUART + kq) * NE;
      candV[cb + l] = selv;
      candI[cb + l] = (unsigned short)(k0 + selk);  // global key index (<2048)
    }
  }
}

// ---------------------------------------------------------------------------
// K4: merge 4x32 quarter candidates per row (2 per lane) -> final top-32 ->
// sorted edges. Same (val desc, idx asc) tie semantics; key indices unique.
// ---------------------------------------------------------------------------
__global__ __launch_bounds__(512) void merge_kernel(const float* __restrict__ candV,
                                                    const unsigned short* __restrict__ candI,
                                                    int* __restrict__ out) {
  const int t = threadIdx.x;
  const int w = t >> 6, l = t & 63;
  const size_t rowg = (size_t)blockIdx.x * 8 + w;  // n*2048 + q
  const int n = (int)(rowg >> 11), q = (int)(rowg & 2047);
  const size_t base = rowg * (NQUART * NE);  // 128 candidates

  float v[2];
  int idx[2];
#pragma unroll
  for (int j = 0; j < 2; ++j) {
    v[j] = candV[base + j * 64 + l];
    idx[j] = (int)candI[base + j * 64 + l];
  }

  int selk = 0;
#pragma unroll 1
  for (int it = 0; it < NE; ++it) {
    float bv = v[0];
    int bi = idx[0];
    if (v[1] > bv || (v[1] == bv && idx[1] < bi)) { bv = v[1]; bi = idx[1]; }
#pragma unroll
    for (int off = 32; off >= 1; off >>= 1) {
      float ov = __shfl_xor(bv, off);
      int oi = __shfl_xor(bi, off);
      if (ov > bv || (ov == bv && oi < bi)) { bv = ov; bi = oi; }
    }
    if (l == it) selk = bi;
#pragma unroll
    for (int j = 0; j < 2; ++j)
      if (idx[j] == bi) v[j] = -1e30f;  // remove winner (unique key idx per row)
  }

  int rank = 0;
#pragma unroll
  for (int j = 0; j < NE; ++j) {
    int o = __shfl(selk, j);
    rank += (o < selk) ? 1 : 0;
  }
  if (l < NE) {
    int* o0 = out + (size_t)n * 2 * LSEQ * NE + (size_t)q * NE;
    int* o1p = o0 + (size_t)LSEQ * NE;
    o0[l] = q;
    o1p[rank] = selk;
  }
}

// ---------------------------------------------------------------------------
extern "C" void kernel_launch(void* const* d_in, const int* in_sizes, int n_in,
                              void* d_out, int out_size, void* d_ws, size_t ws_size,
                              hipStream_t stream) {
  const float* keys = (const float*)d_in[0];
  const float* query = (const float*)d_in[1];
  const float* Wk = (const float*)d_in[2];
  const float* Wq = (const float*)d_in[3];
  int* out = (int*)d_out;

  const size_t SPLIT = (size_t)NB * HH * LSEQ * DD;  // 4,194,304 elems
  __hip_bfloat16* qs1 = (__hip_bfloat16*)d_ws;
  __hip_bfloat16* qs2 = qs1 + SPLIT;
  __hip_bfloat16* qs3 = qs2 + SPLIT;
  __hip_bfloat16* ks1 = qs3 + SPLIT;
  __hip_bfloat16* ks2 = ks1 + SPLIT;
  __hip_bfloat16* ks3 = ks2 + SPLIT;
  float* invp = (float*)(ks3 + SPLIT);                         // 512 KB
  float* candV = invp + (size_t)NB * HH * LSEQ;                // 8.4 MB
  unsigned short* candI =
      (unsigned short*)(candV + (size_t)NB * LSEQ * NQUART * NE);  // 4.2 MB

  proj_kernel<<<NB * LSEQ, 256, 0, stream>>>(query, Wq, 0.0625f * 1.44269504088896340736f,
                                             qs1, qs2, qs3);
  proj_kernel<<<NB * LSEQ, 256, 0, stream>>>(keys, Wk, 1.0f, ks1, ks2, ks3);
  zinv_kernel<<<NB * (LSEQ / ZQT), ZNT, 0, stream>>>(qs1, qs2, qs3, ks1, ks2, ks3, invp);
  mean_topk_kernel<<<NB * (LSEQ / MQT) * NQUART, MNT, 0, stream>>>(
      qs1, qs2, qs3, ks1, ks2, ks3, invp, candV, candI);
  merge_kernel<<<NB * LSEQ / 8, 512, 0, stream>>>(candV, candI, out);
}

// Round 13
// 449.650 us; speedup vs baseline: 3.8186x; 1.6299x over previous
//
#include <hip/hip_runtime.h>
#include <hip/hip_bf16.h>

#define NB 8
#define LSEQ 2048
#define HH 8
#define DD 32
#define EE 256
#define NE 32
#define QT 16      // queries per block (one MFMA tile of rows)
#define NWAVE 16
#define NTH 1024
#define KW 128     // keys per wave (16 waves x 128 = 2048: full row in-block)
#define NTILE 8    // KW / 16
#define SMS 2050   // smean row stride (words)
#define FRAG 96    // interleaved fragment: 3 splits x 32 bf16 per (n,h,l)

typedef __attribute__((ext_vector_type(8))) short short8;
typedef __attribute__((ext_vector_type(4))) float f32x4;

// ---------------------------------------------------------------------------
// K1: per-head projection -> 3-way bf16 split (hi/mid/lo ~ 24 mantissa bits),
// INTERLEAVED layout [n][h][l][3*32]: one base address per fragment triple in
// the consumer; splits at +0/+32/+64 elements (offset:64/128 byte immediates).
// Q pass folds softmax temperature AND 1/ln2: scale = 1/(16*ln2) -> exp2.
// ---------------------------------------------------------------------------
__global__ __launch_bounds__(256) void proj_kernel(const float* __restrict__ x,
                                                   const float* __restrict__ W,
                                                   float scale,
                                                   __hip_bfloat16* __restrict__ o) {
  const int b = blockIdx.x;  // n*L + l
  __shared__ float xs[EE];
  __shared__ float Ws[DD][DD + 1];
  const int t = threadIdx.x;
  xs[t] = x[(size_t)b * EE + t];
  for (int i = t; i < DD * DD; i += 256) Ws[i / DD][i % DD] = W[i];
  __syncthreads();
  const int h = t / DD, e = t % DD;
  float acc = 0.f;
#pragma unroll
  for (int d = 0; d < DD; ++d) acc = fmaf(xs[h * DD + d], Ws[e][d], acc);
  acc *= scale;
  const int n = b / LSEQ, l = b % LSEQ;
  const size_t oi = (((size_t)n * HH + h) * LSEQ + l) * FRAG + e;
  __hip_bfloat16 p1 = __float2bfloat16(acc);
  float r1 = acc - __bfloat162float(p1);
  __hip_bfloat16 p2 = __float2bfloat16(r1);
  float r2 = r1 - __bfloat162float(p2);
  __hip_bfloat16 p3 = __float2bfloat16(r2);
  o[oi] = p1;
  o[oi + 32] = p2;
  o[oi + 64] = p3;
}

// ---------------------------------------------------------------------------
// K2: FUSED energy -> per-head softmax (exp2, no max-sub; bounded energies)
//     -> mean accumulated in REGISTERS -> one-pass LDS redistribute -> top-32.
// The R5/434us structure (best measured), with interleaved fragment loads:
// one address + offset immediates per triple (cuts addr VALU + live regs).
// One block = (n, 16-query tile). 16 waves; wave w owns keys [w*128,(w+1)*128).
// C fragment mapping (verified rounds 2-12): row(query)=g*4+r, col(key)=c.
// ---------------------------------------------------------------------------
__global__ __launch_bounds__(NTH) void attn_topk_kernel(
    const __hip_bfloat16* __restrict__ qp, const __hip_bfloat16* __restrict__ kp,
    int* __restrict__ out) {
  __shared__ float smean[QT * SMS];        // 131 KB: 16 query rows
  __shared__ float wredS[2][QT][NWAVE];    // cross-wave Z partials, dbuf by head parity

  const int t = threadIdx.x;
  const int w = t >> 6, l = t & 63;
  const int g = l >> 4, c = l & 15;  // 16-lane group / lane-in-group
  const int n = blockIdx.x & 7;      // XCD-aligned batch (1024 blocks, %8==0: bijective)
  const int q0 = (blockIdx.x >> 3) * QT;

  float macc[NTILE][4];  // mean-attn accumulator: rows g*4+r, cols w*128+t2*16+c
#pragma unroll
  for (int t2 = 0; t2 < NTILE; ++t2)
#pragma unroll
    for (int r = 0; r < 4; ++r) macc[t2][r] = 0.f;

  for (int h = 0; h < HH; ++h) {
    const size_t hb = ((size_t)n * HH + h) * LSEQ;
    // A fragment (Q): row = c, d-range = g*8..g*8+7; splits at +0/+32/+64
    const __hip_bfloat16* qb = qp + (hb + q0 + c) * FRAG + (size_t)g * 8;
    const short8 aH = *(const short8*)(qb);
    const short8 aM = *(const short8*)(qb + 32);
    const short8 aL = *(const short8*)(qb + 64);

    f32x4 acc[NTILE];
#pragma unroll
    for (int t2 = 0; t2 < NTILE; ++t2) {
      // B fragment (K): col = c, d-range = g*8..g*8+7; splits at +0/+32/+64
      const __hip_bfloat16* kb =
          kp + (hb + (size_t)w * KW + t2 * 16 + c) * FRAG + (size_t)g * 8;
      const short8 bH = *(const short8*)(kb);
      const short8 bM = *(const short8*)(kb + 32);
      const short8 bL = *(const short8*)(kb + 64);
      f32x4 a = {0.f, 0.f, 0.f, 0.f};
      a = __builtin_amdgcn_mfma_f32_16x16x32_bf16(aH, bH, a, 0, 0, 0);
      a = __builtin_amdgcn_mfma_f32_16x16x32_bf16(aH, bM, a, 0, 0, 0);
      a = __builtin_amdgcn_mfma_f32_16x16x32_bf16(aM, bH, a, 0, 0, 0);
      a = __builtin_amdgcn_mfma_f32_16x16x32_bf16(aH, bL, a, 0, 0, 0);
      a = __builtin_amdgcn_mfma_f32_16x16x32_bf16(aL, bH, a, 0, 0, 0);
      a = __builtin_amdgcn_mfma_f32_16x16x32_bf16(aM, bM, a, 0, 0, 0);
      acc[t2] = a;
    }

    // --- exp2 (energies pre-scaled by 1/(16 ln2) in Q proj; bounded) + Z ---
    float Zl[4] = {0.f, 0.f, 0.f, 0.f};
#pragma unroll
    for (int t2 = 0; t2 < NTILE; ++t2) {
#pragma unroll
      for (int r = 0; r < 4; ++r) {
        float e = exp2f(acc[t2][r]);
        acc[t2][r] = e;
        Zl[r] += e;
      }
    }
#pragma unroll
    for (int msk = 1; msk <= 8; msk <<= 1)
#pragma unroll
      for (int r = 0; r < 4; ++r) Zl[r] += __shfl_xor(Zl[r], msk);
    if (c == 0) {
#pragma unroll
      for (int r = 0; r < 4; ++r) wredS[h & 1][g * 4 + r][w] = Zl[r];
    }
    __syncthreads();
    float inv[4];
#pragma unroll
    for (int r = 0; r < 4; ++r) {
      float z = wredS[h & 1][g * 4 + r][c];  // 16 wave partials, c spans them
#pragma unroll
      for (int msk = 1; msk <= 8; msk <<= 1) z += __shfl_xor(z, msk);
      inv[r] = __builtin_amdgcn_rcpf(z);  // per-row monotone scale: order-safe
    }
    // --- accumulate mean rows in registers (mean /8 monotone: skip) ---
#pragma unroll
    for (int t2 = 0; t2 < NTILE; ++t2)
#pragma unroll
      for (int r = 0; r < 4; ++r) macc[t2][r] = fmaf(acc[t2][r], inv[r], macc[t2][r]);
  }

  // --- redistribute all 16 rows to LDS (2-way bank alias max: free) ---
#pragma unroll
  for (int t2 = 0; t2 < NTILE; ++t2)
#pragma unroll
    for (int r = 0; r < 4; ++r)
      smean[(g * 4 + r) * SMS + w * KW + t2 * 16 + c] = macc[t2][r];
  __syncthreads();

  // --- top-32: wave w owns row w (query q0+w); k = j*64 + l ---
  float* row = &smean[w * SMS];
  float vals[32];
  float v1 = -1e30f, v2 = -1e30f;
  int i1 = 1 << 30, i2 = 1 << 30;
#pragma unroll
  for (int j = 0; j < 32; ++j) {
    float v = row[j * 64 + l];
    vals[j] = v;
    const int k = j * 64 + l;
    if (v > v1) { v2 = v1; i2 = i1; v1 = v; i1 = k; }
    else if (v > v2) { v2 = v; i2 = k; }
  }
  unsigned rem = 0u;
  int selk = 0;
#pragma unroll 1
  for (int it = 0; it < NE; ++it) {
    float bv = v1;
    int bk = i1;
#pragma unroll
    for (int off = 32; off >= 1; off >>= 1) {
      float ov = __shfl_xor(bv, off);
      int ok = __shfl_xor(bk, off);
      if (ov > bv || (ov == bv && ok < bk)) { bv = ov; bk = ok; }
    }
    if (l == it) selk = bk;
    if (i1 == bk) {  // this lane supplied the winner (k%64==l: unique owner)
      rem |= 1u << (bk >> 6);
      if (i2 != (1 << 30)) {  // promote cached second
        v1 = v2; i1 = i2;
        v2 = -1e30f; i2 = 1 << 30;
      } else {  // rare: rebuild top-2 from masked registers
        v1 = -1e30f; i1 = 1 << 30;
        v2 = -1e30f; i2 = 1 << 30;
#pragma unroll
        for (int j = 0; j < 32; ++j) {
          float v = ((rem >> j) & 1u) ? -1e30f : vals[j];
          const int k = j * 64 + l;
          if (v > v1) { v2 = v1; i2 = i1; v1 = v; i1 = k; }
          else if (v > v2) { v2 = v; i2 = k; }
        }
      }
    }
  }

  // --- rank-sort the 32 winners by index, write output ---
  int rank = 0;
#pragma unroll
  for (int j = 0; j < NE; ++j) {
    int o = __shfl(selk, j);
    rank += (o < selk) ? 1 : 0;
  }
  const int qg = q0 + w;
  if (l < NE) {
    int* o0 = out + (size_t)n * 2 * LSEQ * NE + (size_t)qg * NE;
    int* o1p = o0 + (size_t)LSEQ * NE;
    o0[l] = qg;
    o1p[rank] = selk;
  }
}

// ---------------------------------------------------------------------------
extern "C" void kernel_launch(void* const* d_in, const int* in_sizes, int n_in,
                              void* d_out, int out_size, void* d_ws, size_t ws_size,
                              hipStream_t stream) {
  const float* keys = (const float*)d_in[0];
  const float* query = (const float*)d_in[1];
  const float* Wk = (const float*)d_in[2];
  const float* Wq = (const float*)d_in[3];
  int* out = (int*)d_out;

  const size_t SIDE = (size_t)NB * HH * LSEQ * FRAG;  // 12.58M elems = 25.2 MB
  __hip_bfloat16* qp = (__hip_bfloat16*)d_ws;
  __hip_bfloat16* kp = qp + SIDE;

  // scale folds softmax temperature (1/16) and 1/ln2 for exp2-based softmax
  proj_kernel<<<NB * LSEQ, 256, 0, stream>>>(query, Wq, 0.0625f * 1.44269504088896340736f, qp);
  proj_kernel<<<NB * LSEQ, 256, 0, stream>>>(keys, Wk, 1.0f, kp);
  attn_topk_kernel<<<NB * (LSEQ / QT), NTH, 0, stream>>>(qp, kp, out);
}